// Round 5
// baseline (4248.362 us; speedup 1.0000x reference)
//
#include <hip/hip_runtime.h>

#define BATCH 16
#define NPTS 16384
#define MCENT 1024
#define NSAMPLE 32
#define PPT 32
#define NTHR 512
#define NWAVE 8

// ---- Morton code: 10 bits, (x:4, y:3, z:3)
__device__ __forceinline__ unsigned morton10(float x, float y, float z) {
    int qx = (int)(x * 16.0f); qx = qx < 0 ? 0 : (qx > 15 ? 15 : qx);
    int qy = (int)(y * 8.0f);  qy = qy < 0 ? 0 : (qy > 7 ? 7 : qy);
    int qz = (int)(z * 8.0f);  qz = qz < 0 ? 0 : (qz > 7 ? 7 : qz);
    unsigned c = 0;
    c |= (unsigned)(qx & 1) | ((unsigned)(qy & 1) << 1) | ((unsigned)(qz & 1) << 2);
    c |= (((unsigned)(qx >> 1) & 1) << 3) | (((unsigned)(qy >> 1) & 1) << 4) | (((unsigned)(qz >> 1) & 1) << 5);
    c |= (((unsigned)(qx >> 2) & 1) << 6) | (((unsigned)(qy >> 2) & 1) << 7) | (((unsigned)(qz >> 2) & 1) << 8);
    c |= (((unsigned)(qx >> 3) & 1) << 9);
    return c;
}

__device__ __forceinline__ unsigned long long shflxor_u64(unsigned long long v, int m) {
    int lo = __shfl_xor((int)(unsigned)v, m, 64);
    int hi = __shfl_xor((int)(unsigned)(v >> 32), m, 64);
    return ((unsigned long long)(unsigned)hi << 32) | (unsigned)lo;
}

// ---------------- setup: Morton counting-sort per batch ----------------
__global__ __launch_bounds__(1024) void sort_kernel(const float* __restrict__ xyz,
                                                    float4* __restrict__ sorted) {
    const int b = blockIdx.x;
    const int tid = threadIdx.x;
    const int lane = tid & 63;
    const int wid = tid >> 6;
    const float* xb = xyz + (size_t)b * NPTS * 3;
    float4* sb = sorted + (size_t)b * NPTS;

    __shared__ unsigned hist[1024];
    __shared__ unsigned wsum[16];
    hist[tid] = 0;
    __syncthreads();

    float mx[16], my[16], mz[16];
    unsigned mc[16];
#pragma unroll
    for (int j = 0; j < 16; ++j) {
        int p = j * 1024 + tid;
        mx[j] = xb[p * 3 + 0];
        my[j] = xb[p * 3 + 1];
        mz[j] = xb[p * 3 + 2];
        mc[j] = morton10(mx[j], my[j], mz[j]);
        atomicAdd(&hist[mc[j]], 1u);
    }
    __syncthreads();

    unsigned orig = hist[tid];
    unsigned v = orig;
#pragma unroll
    for (int off = 1; off < 64; off <<= 1) {
        unsigned n = __shfl_up(v, off);
        if (lane >= off) v += n;
    }
    if (lane == 63) wsum[wid] = v;
    __syncthreads();
    if (wid == 0 && lane < 16) {
        unsigned s = wsum[lane];
#pragma unroll
        for (int off = 1; off < 16; off <<= 1) {
            unsigned n = __shfl_up(s, off);
            if (lane >= off) s += n;
        }
        wsum[lane] = s;
    }
    __syncthreads();
    unsigned base = v - orig + (wid > 0 ? wsum[wid - 1] : 0u);
    __syncthreads();
    hist[tid] = base;
    __syncthreads();

#pragma unroll
    for (int j = 0; j < 16; ++j) {
        int p = j * 1024 + tid;
        unsigned pos = atomicAdd(&hist[mc[j]], 1u);
        sb[pos] = make_float4(mx[j], my[j], mz[j], __int_as_float(p));
    }
}

// ---------------- FPS: 512 threads, 32 pts/thread, forced 2 waves/EU ----------------
__global__ __attribute__((amdgpu_waves_per_eu(2, 2)))
__launch_bounds__(NTHR) void fps_kernel(const float* __restrict__ xyz,
                                        const float4* __restrict__ sorted,
                                        float* __restrict__ cent_out) {
#pragma clang fp contract(off)
    const int b = blockIdx.x;
    const int tid = threadIdx.x;
    const int wid = tid >> 6;
    const float4* sb = sorted + (size_t)b * NPTS;
    const float* xb = xyz + (size_t)b * NPTS * 3;
    float* cb = cent_out + (size_t)b * MCENT * 3;

    float px[PPT], py[PPT], pz[PPT], md[PPT];
    int pid[PPT];
    float l0x = 1e30f, l0y = 1e30f, l0z = 1e30f, h0x = -1e30f, h0y = -1e30f, h0z = -1e30f;
    float l1x = 1e30f, l1y = 1e30f, l1z = 1e30f, h1x = -1e30f, h1y = -1e30f, h1z = -1e30f;
#pragma unroll
    for (int j = 0; j < PPT; ++j) {
        float4 v = sb[tid * PPT + j];
        px[j] = v.x; py[j] = v.y; pz[j] = v.z;
        pid[j] = __float_as_int(v.w);
        md[j] = 1e10f;
        if (j < 16) {
            l0x = fminf(l0x, v.x); h0x = fmaxf(h0x, v.x);
            l0y = fminf(l0y, v.y); h0y = fmaxf(h0y, v.y);
            l0z = fminf(l0z, v.z); h0z = fmaxf(h0z, v.z);
        } else {
            l1x = fminf(l1x, v.x); h1x = fmaxf(h1x, v.x);
            l1y = fminf(l1y, v.y); h1y = fmaxf(h1y, v.y);
            l1z = fminf(l1z, v.z); h1z = fmaxf(h1z, v.z);
        }
    }

    __shared__ unsigned long long skey[2][NWAVE];
    __shared__ float4 scd[2][NWAVE];
    __shared__ float cent_lds[MCENT * 3];

    float cx = xb[0], cy = xb[1], cz = xb[2];

    float bv0 = -1.0f, bv1 = -1.0f;
    int bi0 = 0, bi1 = 0;
    float c0x = 0, c0y = 0, c0z = 0, c1x = 0, c1y = 0, c1z = 0;
    float bxc = 0, byc = 0, bzc = 0;
    unsigned long long mykey = 0, wkey = 0;

    for (int m = 0; m < MCENT; ++m) {
        if (tid == 0) {
            cent_lds[m * 3 + 0] = cx;
            cent_lds[m * 3 + 1] = cy;
            cent_lds[m * 3 + 2] = cz;
        }
        if (m == MCENT - 1) break;

        float tx = fmaxf(fmaxf(l0x - cx, cx - h0x), 0.0f);
        float ty = fmaxf(fmaxf(l0y - cy, cy - h0y), 0.0f);
        float tz = fmaxf(fmaxf(l0z - cz, cz - h0z), 0.0f);
        float lb0 = tx * tx + ty * ty + tz * tz;
        tx = fmaxf(fmaxf(l1x - cx, cx - h1x), 0.0f);
        ty = fmaxf(fmaxf(l1y - cy, cy - h1y), 0.0f);
        tz = fmaxf(fmaxf(l1z - cz, cz - h1z), 0.0f);
        float lb1 = tx * tx + ty * ty + tz * tz;
        bool a0 = (m == 0) || (lb0 * 0.999f < bv0);
        bool a1 = (m == 0) || (lb1 * 0.999f < bv1);

        if (a0) {
            bv0 = -1.0f; bi0 = 0x7fffffff;
#pragma unroll
            for (int j = 0; j < 16; ++j) {
                float dx = px[j] - cx;
                float dy = py[j] - cy;
                float dz = pz[j] - cz;
                float d = dx * dx + dy * dy;
                d = d + dz * dz;
                float nm = fminf(md[j], d);
                md[j] = nm;
                if (nm > bv0 || (nm == bv0 && pid[j] < bi0)) {
                    bv0 = nm; bi0 = pid[j]; c0x = px[j]; c0y = py[j]; c0z = pz[j];
                }
            }
        }
        if (a1) {
            bv1 = -1.0f; bi1 = 0x7fffffff;
#pragma unroll
            for (int j = 16; j < 32; ++j) {
                float dx = px[j] - cx;
                float dy = py[j] - cy;
                float dz = pz[j] - cz;
                float d = dx * dx + dy * dy;
                d = d + dz * dz;
                float nm = fminf(md[j], d);
                md[j] = nm;
                if (nm > bv1 || (nm == bv1 && pid[j] < bi1)) {
                    bv1 = nm; bi1 = pid[j]; c1x = px[j]; c1y = py[j]; c1z = pz[j];
                }
            }
        }
        if (a0 | a1) {
            bool t0 = (bv0 > bv1) || (bv0 == bv1 && bi0 < bi1);
            float bv = t0 ? bv0 : bv1;
            int bi = t0 ? bi0 : bi1;
            bxc = t0 ? c0x : c1x; byc = t0 ? c0y : c1y; bzc = t0 ? c0z : c1z;
            mykey = ((unsigned long long)__float_as_uint(bv) << 32)
                  | (unsigned)(((16383 - bi) << 4) | wid);
        }

        if (__any(a0 | a1)) {
            unsigned long long k = mykey;
#pragma unroll
            for (int off = 1; off <= 32; off <<= 1) {
                unsigned long long o = shflxor_u64(k, off);
                if (o > k) k = o;
            }
            wkey = k;
        }
        const int pb = m & 1;
        if (mykey == wkey) {  // unique owner lane (pid embedded in key)
            skey[pb][wid] = wkey;
            scd[pb][wid] = make_float4(bxc, byc, bzc, 0.0f);
        }
        __syncthreads();

        unsigned long long best = skey[pb][0];
#pragma unroll
        for (int s = 1; s < NWAVE; ++s) {
            unsigned long long t = skey[pb][s];
            if (t > best) best = t;
        }
        float4 w = scd[pb][(unsigned)best & 15u];
        cx = w.x; cy = w.y; cz = w.z;
    }

    __syncthreads();
    for (int i = tid; i < MCENT * 3; i += NTHR) cb[i] = cent_lds[i];
}

// ---------------- Ball query + group ----------------
__global__ __launch_bounds__(256) void ballq_kernel(const float* __restrict__ xyz,
                                                    const float* __restrict__ cent,
                                                    float* __restrict__ grouped) {
#pragma clang fp contract(off)
    const int lane = threadIdx.x & 63;
    const int wib = threadIdx.x >> 6;
    const int cid = blockIdx.x * 4 + wib;
    const int b = cid >> 10;
    const float* xb = xyz + (size_t)b * NPTS * 3;
    const float* c = cent + (size_t)cid * 3;
    float cx = c[0], cy = c[1], cz = c[2];
    float* g = grouped + (size_t)cid * NSAMPLE * 3;

    const float R2 = (float)(0.1 * 0.1);

    int total = 0;
    int first_p = -1;

    for (int p0 = 0; p0 < NPTS && total < NSAMPLE; p0 += 64) {
        int p = p0 + lane;
        float x = xb[p * 3 + 0];
        float y = xb[p * 3 + 1];
        float z = xb[p * 3 + 2];
        float dx = x - cx;
        float dy = y - cy;
        float dz = z - cz;
        float d = dx * dx + dy * dy;
        d = d + dz * dz;
        bool hit = d < R2;
        unsigned long long mask = __ballot(hit);
        if (hit) {
            unsigned int mb = __builtin_amdgcn_mbcnt_lo((unsigned int)mask, 0u);
            mb = __builtin_amdgcn_mbcnt_hi((unsigned int)(mask >> 32), mb);
            int pos = total + (int)mb;
            if (pos < NSAMPLE) {
                g[pos * 3 + 0] = dx;
                g[pos * 3 + 1] = dy;
                g[pos * 3 + 2] = dz;
            }
        }
        if (first_p < 0 && mask != 0ull) first_p = p0 + __builtin_ctzll(mask);
        total += __popcll(mask);
    }

    int sel = total < NSAMPLE ? total : NSAMPLE;
    if (sel < NSAMPLE) {
        float fx = xb[first_p * 3 + 0] - cx;
        float fy = xb[first_p * 3 + 1] - cy;
        float fz = xb[first_p * 3 + 2] - cz;
        int s = lane;
        if (s >= sel && s < NSAMPLE) {
            g[s * 3 + 0] = fx;
            g[s * 3 + 1] = fy;
            g[s * 3 + 2] = fz;
        }
    }
}

extern "C" void kernel_launch(void* const* d_in, const int* in_sizes, int n_in,
                              void* d_out, int out_size, void* d_ws, size_t ws_size,
                              hipStream_t stream) {
    const float* xyz = (const float*)d_in[0];
    float* out = (float*)d_out;
    float* grouped = out;
    float* cent = out + (size_t)BATCH * MCENT * NSAMPLE * 3;
    float4* sorted = (float4*)d_ws;  // 4 MiB

    sort_kernel<<<BATCH, 1024, 0, stream>>>(xyz, sorted);
    fps_kernel<<<BATCH, NTHR, 0, stream>>>(xyz, sorted, cent);
    ballq_kernel<<<(BATCH * MCENT) / 4, 256, 0, stream>>>(xyz, cent, grouped);
}

// Round 6
// 4166.796 us; speedup vs baseline: 1.0196x; 1.0196x over previous
//
#include <hip/hip_runtime.h>

#define BATCH 16
#define NPTS 16384
#define MCENT 1024
#define NSAMPLE 32
#define FTHR 1024
#define FWAVE 16
#define FPPT 16

// ---- Morton code: 10 bits, (x:4, y:3, z:3)
__device__ __forceinline__ unsigned morton10(float x, float y, float z) {
    int qx = (int)(x * 16.0f); qx = qx < 0 ? 0 : (qx > 15 ? 15 : qx);
    int qy = (int)(y * 8.0f);  qy = qy < 0 ? 0 : (qy > 7 ? 7 : qy);
    int qz = (int)(z * 8.0f);  qz = qz < 0 ? 0 : (qz > 7 ? 7 : qz);
    unsigned c = 0;
    c |= (unsigned)(qx & 1) | ((unsigned)(qy & 1) << 1) | ((unsigned)(qz & 1) << 2);
    c |= (((unsigned)(qx >> 1) & 1) << 3) | (((unsigned)(qy >> 1) & 1) << 4) | (((unsigned)(qz >> 1) & 1) << 5);
    c |= (((unsigned)(qx >> 2) & 1) << 6) | (((unsigned)(qy >> 2) & 1) << 7) | (((unsigned)(qz >> 2) & 1) << 8);
    c |= (((unsigned)(qx >> 3) & 1) << 9);
    return c;
}

__device__ __forceinline__ unsigned long long shflxor_u64(unsigned long long v, int m) {
    int lo = __shfl_xor((int)(unsigned)v, m, 64);
    int hi = __shfl_xor((int)(unsigned)(v >> 32), m, 64);
    return ((unsigned long long)(unsigned)hi << 32) | (unsigned)lo;
}

// ---------------- setup: Morton counting-sort per batch ----------------
__global__ __launch_bounds__(1024) void sort_kernel(const float* __restrict__ xyz,
                                                    float4* __restrict__ sorted) {
    const int b = blockIdx.x;
    const int tid = threadIdx.x;
    const int lane = tid & 63;
    const int wid = tid >> 6;
    const float* xb = xyz + (size_t)b * NPTS * 3;
    float4* sb = sorted + (size_t)b * NPTS;

    __shared__ unsigned hist[1024];
    __shared__ unsigned wsum[16];
    hist[tid] = 0;
    __syncthreads();

    float mx[16], my[16], mz[16];
    unsigned mc[16];
#pragma unroll
    for (int j = 0; j < 16; ++j) {
        int p = j * 1024 + tid;
        mx[j] = xb[p * 3 + 0];
        my[j] = xb[p * 3 + 1];
        mz[j] = xb[p * 3 + 2];
        mc[j] = morton10(mx[j], my[j], mz[j]);
        atomicAdd(&hist[mc[j]], 1u);
    }
    __syncthreads();

    unsigned orig = hist[tid];
    unsigned v = orig;
#pragma unroll
    for (int off = 1; off < 64; off <<= 1) {
        unsigned n = __shfl_up(v, off);
        if (lane >= off) v += n;
    }
    if (lane == 63) wsum[wid] = v;
    __syncthreads();
    if (wid == 0 && lane < 16) {
        unsigned s = wsum[lane];
#pragma unroll
        for (int off = 1; off < 16; off <<= 1) {
            unsigned n = __shfl_up(s, off);
            if (lane >= off) s += n;
        }
        wsum[lane] = s;
    }
    __syncthreads();
    unsigned base = v - orig + (wid > 0 ? wsum[wid - 1] : 0u);
    __syncthreads();
    hist[tid] = base;
    __syncthreads();

#pragma unroll
    for (int j = 0; j < 16; ++j) {
        int p = j * 1024 + tid;
        unsigned pos = atomicAdd(&hist[mc[j]], 1u);
        sb[pos] = make_float4(mx[j], my[j], mz[j], __int_as_float(p));
    }
}

// ---------------- FPS: 1024 threads, 16 pts/thread, ~115 VGPRs ----------------
__global__ __attribute__((amdgpu_waves_per_eu(4, 4)))
__launch_bounds__(FTHR, 4) void fps_kernel(const float* __restrict__ xyz,
                                           const float4* __restrict__ sorted,
                                           float* __restrict__ cent_out) {
#pragma clang fp contract(off)
    const int b = blockIdx.x;
    const int tid = threadIdx.x;
    const int wid = tid >> 6;
    const float4* sb = sorted + (size_t)b * NPTS;
    const float* xb = xyz + (size_t)b * NPTS * 3;
    float* cb = cent_out + (size_t)b * MCENT * 3;

    float px[FPPT], py[FPPT], pz[FPPT], md[FPPT];
    unsigned pidp[FPPT / 2];  // packed u16 original indices
    float lx = 1e30f, ly = 1e30f, lz = 1e30f, hx = -1e30f, hy = -1e30f, hz = -1e30f;
#pragma unroll
    for (int j = 0; j < FPPT; ++j) {
        float4 v = sb[tid * FPPT + j];
        px[j] = v.x; py[j] = v.y; pz[j] = v.z;
        md[j] = 1e10f;
        unsigned pidj = (unsigned)__float_as_int(v.w);
        if ((j & 1) == 0) pidp[j >> 1] = pidj;
        else pidp[j >> 1] |= pidj << 16;
        lx = fminf(lx, v.x); hx = fmaxf(hx, v.x);
        ly = fminf(ly, v.y); hy = fmaxf(hy, v.y);
        lz = fminf(lz, v.z); hz = fmaxf(hz, v.z);
    }

    __shared__ unsigned long long skey[2][FWAVE];
    __shared__ float4 scd[2][FWAVE];
    __shared__ float cent_lds[MCENT * 3];

    float cx = xb[0], cy = xb[1], cz = xb[2];

    // cached per-thread best (valid while pruned: md can only decrease, and
    // pruning proves no md in this thread changed)
    float bv = -1.0f; int bpid = 0x7fffffff;
    float bx = 0.f, by = 0.f, bz = 0.f;
    unsigned long long mykey = 0, wkey = 0;

    for (int m = 0; m < MCENT; ++m) {
        if (tid == 0) {
            cent_lds[m * 3 + 0] = cx;
            cent_lds[m * 3 + 1] = cy;
            cent_lds[m * 3 + 2] = cz;
        }
        if (m == MCENT - 1) break;

        // exact prune: skip when provably no md in this thread's 16 pts changes
        float tx = fmaxf(fmaxf(lx - cx, cx - hx), 0.0f);
        float ty = fmaxf(fmaxf(ly - cy, cy - hy), 0.0f);
        float tz = fmaxf(fmaxf(lz - cz, cz - hz), 0.0f);
        float lb = tx * tx + ty * ty;
        lb = lb + tz * tz;
        bool active = (m == 0) || (lb * 0.999f < bv);

        if (active) {
            bv = -1.0f; bpid = 0x7fffffff;
#pragma unroll
            for (int j = 0; j < FPPT; ++j) {
                float dx = px[j] - cx;
                float dy = py[j] - cy;
                float dz = pz[j] - cz;
                float d = dx * dx + dy * dy;
                d = d + dz * dz;
                float nm = fminf(md[j], d);
                md[j] = nm;
                int pidj = (int)((j & 1) ? (pidp[j >> 1] >> 16) : (pidp[j >> 1] & 0xffffu));
                if (nm > bv || (nm == bv && pidj < bpid)) {
                    bv = nm; bpid = pidj;
                    bx = px[j]; by = py[j]; bz = pz[j];
                }
            }
            mykey = ((unsigned long long)__float_as_uint(bv) << 32)
                  | (unsigned)(((16383 - bpid) << 4) | wid);
        }

        // in-wave u64-max butterfly only if some lane recomputed
        if (__any(active)) {
            unsigned long long k = mykey;
#pragma unroll
            for (int off = 1; off <= 32; off <<= 1) {
                unsigned long long o = shflxor_u64(k, off);
                if (o > k) k = o;
            }
            wkey = k;
        }
        const int pb = m & 1;
        if (mykey == wkey) {  // unique owner (pid embedded); executes every iter
            skey[pb][wid] = wkey;
            scd[pb][wid] = make_float4(bx, by, bz, 0.0f);
        }
        __syncthreads();

        // every wave redundantly reduces 16 slots: 8 paired loads + depth-4 tree
        unsigned long long t[8];
#pragma unroll
        for (int s = 0; s < 8; ++s) {
            unsigned long long a = skey[pb][2 * s];
            unsigned long long c = skey[pb][2 * s + 1];
            t[s] = a > c ? a : c;
        }
#pragma unroll
        for (int st = 4; st >= 1; st >>= 1) {
#pragma unroll
            for (int s = 0; s < st; ++s)
                if (t[s + st] > t[s]) t[s] = t[s + st];
        }
        float4 w = scd[pb][(unsigned)t[0] & 15u];
        cx = w.x; cy = w.y; cz = w.z;
    }

    __syncthreads();
    for (int i = tid; i < MCENT * 3; i += FTHR) cb[i] = cent_lds[i];
}

// ---------------- Ball query + group ----------------
__global__ __launch_bounds__(256) void ballq_kernel(const float* __restrict__ xyz,
                                                    const float* __restrict__ cent,
                                                    float* __restrict__ grouped) {
#pragma clang fp contract(off)
    const int lane = threadIdx.x & 63;
    const int wib = threadIdx.x >> 6;
    const int cid = blockIdx.x * 4 + wib;
    const int b = cid >> 10;
    const float* xb = xyz + (size_t)b * NPTS * 3;
    const float* c = cent + (size_t)cid * 3;
    float cx = c[0], cy = c[1], cz = c[2];
    float* g = grouped + (size_t)cid * NSAMPLE * 3;

    const float R2 = (float)(0.1 * 0.1);

    int total = 0;
    int first_p = -1;

    for (int p0 = 0; p0 < NPTS && total < NSAMPLE; p0 += 64) {
        int p = p0 + lane;
        float x = xb[p * 3 + 0];
        float y = xb[p * 3 + 1];
        float z = xb[p * 3 + 2];
        float dx = x - cx;
        float dy = y - cy;
        float dz = z - cz;
        float d = dx * dx + dy * dy;
        d = d + dz * dz;
        bool hit = d < R2;
        unsigned long long mask = __ballot(hit);
        if (hit) {
            unsigned int mb = __builtin_amdgcn_mbcnt_lo((unsigned int)mask, 0u);
            mb = __builtin_amdgcn_mbcnt_hi((unsigned int)(mask >> 32), mb);
            int pos = total + (int)mb;
            if (pos < NSAMPLE) {
                g[pos * 3 + 0] = dx;
                g[pos * 3 + 1] = dy;
                g[pos * 3 + 2] = dz;
            }
        }
        if (first_p < 0 && mask != 0ull) first_p = p0 + __builtin_ctzll(mask);
        total += __popcll(mask);
    }

    int sel = total < NSAMPLE ? total : NSAMPLE;
    if (sel < NSAMPLE) {
        float fx = xb[first_p * 3 + 0] - cx;
        float fy = xb[first_p * 3 + 1] - cy;
        float fz = xb[first_p * 3 + 2] - cz;
        int s = lane;
        if (s >= sel && s < NSAMPLE) {
            g[s * 3 + 0] = fx;
            g[s * 3 + 1] = fy;
            g[s * 3 + 2] = fz;
        }
    }
}

extern "C" void kernel_launch(void* const* d_in, const int* in_sizes, int n_in,
                              void* d_out, int out_size, void* d_ws, size_t ws_size,
                              hipStream_t stream) {
    const float* xyz = (const float*)d_in[0];
    float* out = (float*)d_out;
    float* grouped = out;
    float* cent = out + (size_t)BATCH * MCENT * NSAMPLE * 3;
    float4* sorted = (float4*)d_ws;  // 4 MiB

    sort_kernel<<<BATCH, 1024, 0, stream>>>(xyz, sorted);
    fps_kernel<<<BATCH, FTHR, 0, stream>>>(xyz, sorted, cent);
    ballq_kernel<<<(BATCH * MCENT) / 4, 256, 0, stream>>>(xyz, cent, grouped);
}